// Round 22
// baseline (103.485 us; speedup 1.0000x reference)
//
#include <hip/hip_runtime.h>
#include <hip/hip_bf16.h>

typedef unsigned short u16;
typedef unsigned int u32;
typedef __bf16 bf16x8 __attribute__((ext_vector_type(8)));
typedef float f32x4 __attribute__((ext_vector_type(4)));
typedef u32 u32x4 __attribute__((ext_vector_type(4)));

#define MFMA16(a, b, c) __builtin_amdgcn_mfma_f32_16x16x32_bf16((a), (b), (c), 0, 0, 0)

static __device__ __forceinline__ u16 f2bf(float f) {
  __hip_bfloat16 h = __float2bfloat16(f);
  return __builtin_bit_cast(u16, h);
}

static __device__ __forceinline__ u32 pack2(float a, float b) {
  return (u32)f2bf(a) | ((u32)f2bf(b) << 16);
}

static __device__ __forceinline__ bf16x8 ldbf8(const void* p) {
  return *reinterpret_cast<const bf16x8*>(p);
}

static __device__ __forceinline__ void gload_lds16(const void* g, void* l) {
  __builtin_amdgcn_global_load_lds(
      (const __attribute__((address_space(1))) u32*)g,
      (__attribute__((address_space(3))) u32*)l, 16, 0, 0);
}

// ---------------------------------------------------------------- cvt f32->bf16 (fused x, W_qkv, W_o)
__global__ void cvt_all(const float* __restrict__ x, const float* __restrict__ wq,
                        const float* __restrict__ wo, u16* __restrict__ xb,
                        u16* __restrict__ wqb, u16* __restrict__ wob) {
  int i = blockIdx.x * 256 + threadIdx.x;  // grid 4096 -> 1,048,576 threads
  const float* s;
  u16* d;
  int j;
  if (i < 524288) {
    s = x; d = xb; j = i;
  } else if (i < 917504) {
    s = wq; d = wqb; j = i - 524288;
  } else {
    s = wo; d = wob; j = i - 917504;
  }
  const float4* p = reinterpret_cast<const float4*>(s) + (size_t)j * 2;
  float4 a = p[0], b = p[1];
  uint4 o;
  o.x = (u32)f2bf(a.x) | ((u32)f2bf(a.y) << 16);
  o.y = (u32)f2bf(a.z) | ((u32)f2bf(a.w) << 16);
  o.z = (u32)f2bf(b.x) | ((u32)f2bf(b.y) << 16);
  o.w = (u32)f2bf(b.z) | ((u32)f2bf(b.w) << 16);
  reinterpret_cast<uint4*>(d)[j] = o;
}

// ---------------------------------------------------------------- GEMM C = A*B^T + bias
// 128x128 tile, BK=64, 4 waves; 3 blocks/CU; XCD-chunked block remap.
template <bool BF16OUT>
__global__ __launch_bounds__(256, 3) void gemm_bt(const u16* __restrict__ A,
                                                  const u16* __restrict__ Bm,
                                                  const float* __restrict__ bias,
                                                  void* __restrict__ Cp,
                                                  int M, int N, int K) {
  __shared__ __align__(16) char As[128 * 64 * 2];
  __shared__ __align__(16) char Bs[128 * 64 * 2];
  const int tid = threadIdx.x;
  const int lane = tid & 63;
  const int wid = tid >> 6;
  const int fr = lane & 15, fg = lane >> 4;
  // XCD-aware bijective remap (nwg % 8 == 0 for both call sites)
  const int gx = gridDim.x, nwg = gx * gridDim.y;
  const int id = blockIdx.y * gx + blockIdx.x;
  const int nid = (id & 7) * (nwg >> 3) + (id >> 3);
  const int bm = nid / gx, bn = nid % gx;
  const int wm = (wid >> 1) * 64, wn = (wid & 1) * 64;

  f32x4 acc[4][4];
#pragma unroll
  for (int i = 0; i < 4; ++i)
#pragma unroll
    for (int j = 0; j < 4; ++j) acc[i][j] = (f32x4){0.f, 0.f, 0.f, 0.f};

  const int nk = K >> 6;
  for (int kt = 0; kt < nk; ++kt) {
#pragma unroll
    for (int it = 0; it < 4; ++it) {
      int q = it * 256 + tid;
      int row = q >> 3;
      int c = (q & 7) ^ (row & 7);  // pre-swizzled source chunk
      gload_lds16(A + (size_t)(bm * 128 + row) * K + kt * 64 + c * 8, As + q * 16);
      gload_lds16(Bm + (size_t)(bn * 128 + row) * K + kt * 64 + c * 8, Bs + q * 16);
    }
    __syncthreads();
#pragma unroll
    for (int mk = 0; mk < 2; ++mk) {
      bf16x8 af[4], bfr[4];
#pragma unroll
      for (int i = 0; i < 4; ++i) {
        int row = wm + i * 16 + fr;
        af[i] = ldbf8(As + ((row * 128 + mk * 64 + fg * 16) ^ ((row & 7) << 4)));
      }
#pragma unroll
      for (int j = 0; j < 4; ++j) {
        int row = wn + j * 16 + fr;
        bfr[j] = ldbf8(Bs + ((row * 128 + mk * 64 + fg * 16) ^ ((row & 7) << 4)));
      }
#pragma unroll
      for (int i = 0; i < 4; ++i)
#pragma unroll
        for (int j = 0; j < 4; ++j) acc[i][j] = MFMA16(af[i], bfr[j], acc[i][j]);
    }
    __syncthreads();
  }

#pragma unroll
  for (int j = 0; j < 4; ++j) {
    int col = bn * 128 + wn + j * 16 + fr;
    float bv = bias[col];
#pragma unroll
    for (int i = 0; i < 4; ++i) {
#pragma unroll
      for (int r = 0; r < 4; ++r) {
        int row = bm * 128 + wm + i * 16 + fg * 4 + r;
        float v = acc[i][j][r] + bv;
        if (BF16OUT)
          ((u16*)Cp)[(size_t)row * N + col] = f2bf(v);
        else
          ((float*)Cp)[(size_t)row * N + col] = v;
      }
    }
  }
}

// ---------------------------------------------------------------- GEMM 64x128 tile (fp32 out)
__global__ __launch_bounds__(256, 2) void gemm_bt64(const u16* __restrict__ A,
                                                    const u16* __restrict__ Bm,
                                                    const float* __restrict__ bias,
                                                    float* __restrict__ Cp,
                                                    int M, int N, int K) {
  __shared__ __align__(16) char As[64 * 64 * 2];
  __shared__ __align__(16) char Bs[128 * 64 * 2];
  const int tid = threadIdx.x;
  const int lane = tid & 63;
  const int wid = tid >> 6;
  const int fr = lane & 15, fg = lane >> 4;
  const int gx = gridDim.x, nwg = gx * gridDim.y;
  const int id = blockIdx.y * gx + blockIdx.x;
  const int nid = (id & 7) * (nwg >> 3) + (id >> 3);
  const int bm = nid / gx, bn = nid % gx;
  const int wm = (wid >> 1) * 32, wn = (wid & 1) * 64;

  f32x4 acc[2][4];
#pragma unroll
  for (int i = 0; i < 2; ++i)
#pragma unroll
    for (int j = 0; j < 4; ++j) acc[i][j] = (f32x4){0.f, 0.f, 0.f, 0.f};

  const int nk = K >> 6;
  for (int kt = 0; kt < nk; ++kt) {
#pragma unroll
    for (int it = 0; it < 2; ++it) {  // A: 512 chunks
      int q = it * 256 + tid;
      int row = q >> 3;
      int c = (q & 7) ^ (row & 7);
      gload_lds16(A + (size_t)(bm * 64 + row) * K + kt * 64 + c * 8, As + q * 16);
    }
#pragma unroll
    for (int it = 0; it < 4; ++it) {  // B: 1024 chunks
      int q = it * 256 + tid;
      int row = q >> 3;
      int c = (q & 7) ^ (row & 7);
      gload_lds16(Bm + (size_t)(bn * 128 + row) * K + kt * 64 + c * 8, Bs + q * 16);
    }
    __syncthreads();
#pragma unroll
    for (int mk = 0; mk < 2; ++mk) {
      bf16x8 af[2], bfr[4];
#pragma unroll
      for (int i = 0; i < 2; ++i) {
        int row = wm + i * 16 + fr;
        af[i] = ldbf8(As + ((row * 128 + mk * 64 + fg * 16) ^ ((row & 7) << 4)));
      }
#pragma unroll
      for (int j = 0; j < 4; ++j) {
        int row = wn + j * 16 + fr;
        bfr[j] = ldbf8(Bs + ((row * 128 + mk * 64 + fg * 16) ^ ((row & 7) << 4)));
      }
#pragma unroll
      for (int i = 0; i < 2; ++i)
#pragma unroll
        for (int j = 0; j < 4; ++j) acc[i][j] = MFMA16(af[i], bfr[j], acc[i][j]);
    }
    __syncthreads();
  }

#pragma unroll
  for (int j = 0; j < 4; ++j) {
    int col = bn * 128 + wn + j * 16 + fr;
    float bv = bias[col];
#pragma unroll
    for (int i = 0; i < 2; ++i) {
#pragma unroll
      for (int r = 0; r < 4; ++r) {
        int row = bm * 64 + wm + i * 16 + fg * 4 + r;
        Cp[(size_t)row * N + col] = acc[i][j][r] + bv;
      }
    }
  }
}

// ---------------------------------------------------------------- flash attention v16
// R21 + vectorized V staging: each staging thread owns 8 phys keys
// {32m+16u+4g+e : u,e} which the shuffle-free map sends to CONTIGUOUS logical
// slots L0+[0,8), L0 = 32m+8g -> V staged as 4 ds_write_b128/thread (vs 16
// b32). LDS image bit-identical; read side unchanged. V global loads become
// 16 coalesced dwords/thread; counted barrier becomes vmcnt(16).
__global__ __launch_bounds__(256, 2) void attn_fwd(const u16* __restrict__ qkv,
                                                   u16* __restrict__ aout) {
  const int id = blockIdx.y * gridDim.x + blockIdx.x;  // 0..511
  const int xcd = id & 7, slot = id >> 3;
  const int bh = xcd * 4 + (slot >> 4);
  const int qt = slot & 15;
  const int b = bh >> 4, h = bh & 15;
  const int tid = threadIdx.x, lane = tid & 63, wid = tid >> 6;
  const int fr = lane & 15, fg = (lane >> 4) & 3;

  __shared__ __align__(16) char Ks[2][2][64 * 128];   // [buf][sub] swizzled [key][d]
  __shared__ __align__(16) char VTs[2][2][64 * 128];  // [buf][sub] swizzled [d][lkey]

  const int q0 = qt * 128 + wid * 32;  // 32 q-rows per wave
  const size_t bS = (size_t)b * 2048;
  const u16* kbase = qkv + bS * 3072 + h * 192 + 64;
  const u16* vbase = qkv + bS * 3072 + h * 192 + 128;

  // ---- V staging geometry: group G = tid>>5 -> vm=G>>2, vg=G&3; d-pair dp ----
  const int vG = tid >> 5;
  const int vm = vG >> 2, vg = vG & 3;
  const int dp = (tid & 31) * 2;
  const int vL0 = 32 * vm + 8 * vg;  // contiguous logical block [vL0, vL0+8)
  int wof2[2];
#pragma unroll
  for (int dd = 0; dd < 2; ++dd) {
    int d = dp + dd;
    wof2[dd] = ((d * 128 + vL0 * 2) ^ ((((d & 7) ^ ((d >> 3) & 7))) << 4));
    asm volatile("" : "+v"(wof2[dd]));
  }
  int kro[2];
#pragma unroll
  for (int mk = 0; mk < 2; ++mk) {
    kro[mk] = ((fr * 128 + mk * 64 + fg * 16) ^ ((fr & 7) << 4));
    asm volatile("" : "+v"(kro[mk]));
  }
  int vadr[4][2];
#pragma unroll
  for (int tp = 0; tp < 4; ++tp)
#pragma unroll
    for (int mk = 0; mk < 2; ++mk) {
      int d = tp * 16 + fr;
      int swz = (((d & 7) ^ ((d >> 3) & 7)) << 4);
      vadr[tp][mk] = ((d * 128 + mk * 64 + fg * 16) ^ swz);
      asm volatile("" : "+v"(vadr[tp][mk]));
    }

  bf16x8 qf[2][2];
#pragma unroll
  for (int qs = 0; qs < 2; ++qs)
#pragma unroll
    for (int mk = 0; mk < 2; ++mk) {
      bf16x8 v =
          ldbf8(qkv + (bS + q0 + qs * 16 + fr) * 3072 + h * 192 + mk * 32 + fg * 8);
#pragma unroll
      for (int e = 0; e < 8; ++e) v[e] = (__bf16)((float)v[e] * 0.1803368801f);
      qf[qs][mk] = v;
    }

  const u32 one2 = 0x3F803F80u;
  const u32x4 onev = {one2, one2, one2, one2};
  const bf16x8 onesf = __builtin_bit_cast(bf16x8, onev);
  float zs = 0.f;
  asm volatile("" : "+v"(zs));
  const f32x4 zacc = {zs, zs, zs, zs};

  f32x4 oacc0[4], oacc1[4];
#pragma unroll
  for (int t = 0; t < 4; ++t) {
    oacc0[t] = (f32x4){0.f, 0.f, 0.f, 0.f};
    oacc1[t] = (f32x4){0.f, 0.f, 0.f, 0.f};
  }
  f32x4 lacc0 = (f32x4){0.f, 0.f, 0.f, 0.f};
  f32x4 lacc1 = (f32x4){0.f, 0.f, 0.f, 0.f};

// K tile (128 keys) -> Ks[BUF] via 4 gload_lds/thread (pre-swizzled source)
#define KISSUE(S0, BUF)                                                        \
  _Pragma("unroll") for (int it = 0; it < 2; ++it) {                           \
    int q = it * 256 + tid;                                                    \
    int row = q >> 3;                                                          \
    int c = (q & 7) ^ (row & 7);                                               \
    gload_lds16(kbase + (size_t)((S0) + row) * 3072 + c * 8,                   \
                Ks[BUF][0] + q * 16);                                          \
    gload_lds16(kbase + (size_t)((S0) + 64 + row) * 3072 + c * 8,              \
                Ks[BUF][1] + q * 16);                                          \
  }

// V tile: 16 dwords/thread; VA is u32[16]: [sub*8 + u*4 + e]
#define LOADV(S0, VA)                                                          \
  _Pragma("unroll") for (int sub = 0; sub < 2; ++sub)                          \
      _Pragma("unroll") for (int u = 0; u < 2; ++u)                            \
          _Pragma("unroll") for (int e = 0; e < 4; ++e) {                      \
    int s = sub * 64 + 32 * vm + 16 * u + 4 * vg + e;                          \
    VA[sub * 8 + u * 4 + e] = *reinterpret_cast<const u32*>(                   \
        vbase + (size_t)((S0) + s) * 3072 + dp);                               \
  }

// pack 8 dwords (keys L0..L0+7 at d=dp low / dp+1 high) -> two b128 writes
#define STAGEV1(VTP, VP, OFS)                                                  \
  {                                                                            \
    u32x4 lo, hi;                                                              \
    lo.x = (VP[(OFS) + 0] & 0xFFFFu) | (VP[(OFS) + 1] << 16);                  \
    lo.y = (VP[(OFS) + 2] & 0xFFFFu) | (VP[(OFS) + 3] << 16);                  \
    lo.z = (VP[(OFS) + 4] & 0xFFFFu) | (VP[(OFS) + 5] << 16);                  \
    lo.w = (VP[(OFS) + 6] & 0xFFFFu) | (VP[(OFS) + 7] << 16);                  \
    hi.x = (VP[(OFS) + 0] >> 16) | (VP[(OFS) + 1] & 0xFFFF0000u);              \
    hi.y = (VP[(OFS) + 2] >> 16) | (VP[(OFS) + 3] & 0xFFFF0000u);              \
    hi.z = (VP[(OFS) + 4] >> 16) | (VP[(OFS) + 5] & 0xFFFF0000u);              \
    hi.w = (VP[(OFS) + 6] >> 16) | (VP[(OFS) + 7] & 0xFFFF0000u);              \
    *reinterpret_cast<u32x4*>((VTP) + wof2[0]) = lo;                           \
    *reinterpret_cast<u32x4*>((VTP) + wof2[1]) = hi;                           \
  }

#define STAGEV(BUF, VA)              \
  {                                  \
    STAGEV1(VTs[BUF][0], VA, 0);     \
    STAGEV1(VTs[BUF][1], VA, 8);     \
  }

// counted barrier: K(t+1) gloads (4, oldest) drained; V(t+2) dwords (16) fly
#define BARC()                                                   \
  {                                                              \
    __builtin_amdgcn_sched_barrier(0);                           \
    asm volatile("s_waitcnt vmcnt(16) lgkmcnt(0)" ::: "memory"); \
    __builtin_amdgcn_s_barrier();                                \
    __builtin_amdgcn_sched_barrier(0);                           \
  }

#define COMPUTE1(KSP, VTP)                                                     \
  {                                                                            \
    f32x4 sc0[4], sc1[4];                                                      \
    __builtin_amdgcn_s_setprio(1);                                             \
    _Pragma("unroll") for (int t = 0; t < 4; ++t) {                            \
      bf16x8 kf0 = ldbf8((KSP) + kro[0] + t * 2048);                           \
      bf16x8 kf1 = ldbf8((KSP) + kro[1] + t * 2048);                           \
      sc0[t] = MFMA16(kf0, qf[0][0], zacc);                                    \
      sc0[t] = MFMA16(kf1, qf[0][1], sc0[t]);                                  \
      sc1[t] = MFMA16(kf0, qf[1][0], zacc);                                    \
      sc1[t] = MFMA16(kf1, qf[1][1], sc1[t]);                                  \
    }                                                                          \
    __builtin_amdgcn_s_setprio(0);                                             \
    u32 Wp0[2][4], Wp1[2][4];                                                  \
    _Pragma("unroll") for (int t = 0; t < 4; ++t) {                            \
      Wp0[0][t] = pack2(__builtin_amdgcn_exp2f(sc0[t][0]),                     \
                        __builtin_amdgcn_exp2f(sc0[t][1]));                    \
      Wp0[1][t] = pack2(__builtin_amdgcn_exp2f(sc0[t][2]),                     \
                        __builtin_amdgcn_exp2f(sc0[t][3]));                    \
      Wp1[0][t] = pack2(__builtin_amdgcn_exp2f(sc1[t][0]),                     \
                        __builtin_amdgcn_exp2f(sc1[t][1]));                    \
      Wp1[1][t] = pack2(__builtin_amdgcn_exp2f(sc1[t][2]),                     \
                        __builtin_amdgcn_exp2f(sc1[t][3]));                    \
    }                                                                          \
    _Pragma("unroll") for (int mk = 0; mk < 2; ++mk) {                         \
      u32x4 pk0, pk1;                                                          \
      pk0.x = Wp0[0][2 * mk];                                                  \
      pk0.y = Wp0[1][2 * mk];                                                  \
      pk0.z = Wp0[0][2 * mk + 1];                                              \
      pk0.w = Wp0[1][2 * mk + 1];                                              \
      pk1.x = Wp1[0][2 * mk];                                                  \
      pk1.y = Wp1[1][2 * mk];                                                  \
      pk1.z = Wp1[0][2 * mk + 1];                                              \
      pk1.w = Wp1[1][2 * mk + 1];                                              \
      bf16x8 pa0 = __builtin_bit_cast(bf16x8, pk0);                            \
      bf16x8 pa1 = __builtin_bit_cast(bf16x8, pk1);                            \
      __builtin_amdgcn_s_setprio(1);                                           \
      lacc0 = MFMA16(pa0, onesf, lacc0);                                       \
      lacc1 = MFMA16(pa1, onesf, lacc1);                                       \
      _Pragma("unroll") for (int tp = 0; tp < 4; ++tp) {                       \
        bf16x8 vf = ldbf8((VTP) + vadr[tp][mk]);                               \
        oacc0[tp] = MFMA16(pa0, vf, oacc0[tp]);                                \
        oacc1[tp] = MFMA16(pa1, vf, oacc1[tp]);                                \
      }                                                                        \
      __builtin_amdgcn_s_setprio(0);                                           \
    }                                                                          \
  }

#define COMPUTE(BUF)                   \
  {                                    \
    COMPUTE1(Ks[BUF][0], VTs[BUF][0]); \
    COMPUTE1(Ks[BUF][1], VTs[BUF][1]); \
  }

  u32 va[16], vb[16];
  // prologue: K(0)->Ks[0] (gload); V(0)->va->VTs[0]; V(1)->vb; barrier.
  // STAGEV's use of va drains K(0) (older) for this wave; barrier publishes.
  // At BARC outstanding = vb's 16 dwords only -> vmcnt(16) waits nothing
  // extra, which is correct: K(0) already drained.
  KISSUE(0, 0);
  __builtin_amdgcn_sched_barrier(0);
  LOADV(0, va);
  STAGEV(0, va);
  LOADV(128, vb);
  BARC();
  for (int kv = 0; kv < 16; kv += 2) {
    // phase A (tile kv, buf0): K(kv+1)->Ks[1]; V(kv+2)->va; V(kv+1)->VTs[1]
    {
      int sk = (kv + 1 < 16) ? (kv + 1) * 128 : 0;  // tail: harmless write
      KISSUE(sk, 1);
    }
    __builtin_amdgcn_sched_barrier(0);
    {
      int sv = (kv + 2 < 16) ? (kv + 2) * 128 : 0;  // tail: harmless load
      LOADV(sv, va);
    }
    STAGEV(1, vb);
    COMPUTE(0);
    BARC();
    // phase B (tile kv+1, buf1): K(kv+2)->Ks[0]; V(kv+3)->vb; V(kv+2)->VTs[0]
    {
      int sk = (kv + 2 < 16) ? (kv + 2) * 128 : 0;
      KISSUE(sk, 0);
    }
    __builtin_amdgcn_sched_barrier(0);
    {
      int sv = (kv + 3 < 16) ? (kv + 3) * 128 : 128;
      LOADV(sv, vb);
    }
    STAGEV(0, va);
    COMPUTE(1);
    BARC();
  }
#undef KISSUE
#undef LOADV
#undef STAGEV1
#undef STAGEV
#undef BARC
#undef COMPUTE1
#undef COMPUTE

  {
    float invb0[4], invb1[4];
#pragma unroll
    for (int r = 0; r < 4; ++r) {
      invb0[r] = 1.f / lacc0[r];
      invb1[r] = 1.f / lacc1[r];
    }
#pragma unroll
    for (int tp = 0; tp < 4; ++tp) {
#pragma unroll
      for (int r = 0; r < 4; ++r) {
        int row0 = q0 + fg * 4 + r;
        aout[(bS + row0) * 1024 + h * 64 + tp * 16 + fr] =
            f2bf(oacc0[tp][r] * invb0[r]);
        int row1 = q0 + 16 + fg * 4 + r;
        aout[(bS + row1) * 1024 + h * 64 + tp * 16 + fr] =
            f2bf(oacc1[tp][r] * invb1[r]);
      }
    }
  }
}

// ---------------------------------------------------------------- launch
extern "C" void kernel_launch(void* const* d_in, const int* in_sizes, int n_in,
                              void* d_out, int out_size, void* d_ws, size_t ws_size,
                              hipStream_t stream) {
  const float* x = (const float*)d_in[0];
  const float* Wqkv = (const float*)d_in[1];
  const float* bqkv = (const float*)d_in[2];
  const float* Wo = (const float*)d_in[3];
  const float* bo = (const float*)d_in[4];
  float* out = (float*)d_out;
  char* ws = (char*)d_ws;

  u16* xb = (u16*)(ws);                       //  8,388,608  x bf16 [4096,1024]
  u16* wqb = (u16*)(ws + 8388608);            //  6,291,456  W_qkv bf16 [3072,1024]
  u16* wob = (u16*)(ws + 14680064);           //  2,097,152  W_o bf16 [1024,1024]
  u16* qkvb = (u16*)(ws + 16777216);          // 25,165,824  qkv bf16 [4096,3072]
  u16* attb = (u16*)(ws + 41943040);          //  8,388,608  attn out bf16 [4096,1024]

  cvt_all<<<4096, 256, 0, stream>>>(x, Wqkv, Wo, xb, wqb, wob);

  gemm_bt<true><<<dim3(24, 32), 256, 0, stream>>>(xb, wqb, bqkv, qkvb, 4096, 3072, 1024);
  attn_fwd<<<dim3(16, 32), 256, 0, stream>>>(qkvb, attb);
  gemm_bt64<<<dim3(8, 64), 256, 0, stream>>>(attb, wob, bo, out, 4096, 1024, 1024);
}

// Round 23
// 102.709 us; speedup vs baseline: 1.0076x; 1.0076x over previous
//
#include <hip/hip_runtime.h>
#include <hip/hip_bf16.h>

typedef unsigned short u16;
typedef unsigned int u32;
typedef __bf16 bf16x8 __attribute__((ext_vector_type(8)));
typedef float f32x4 __attribute__((ext_vector_type(4)));
typedef u32 u32x4 __attribute__((ext_vector_type(4)));

#define MFMA16(a, b, c) __builtin_amdgcn_mfma_f32_16x16x32_bf16((a), (b), (c), 0, 0, 0)

static __device__ __forceinline__ u16 f2bf(float f) {
  __hip_bfloat16 h = __float2bfloat16(f);
  return __builtin_bit_cast(u16, h);
}

static __device__ __forceinline__ u32 pack2(float a, float b) {
  return (u32)f2bf(a) | ((u32)f2bf(b) << 16);
}

static __device__ __forceinline__ bf16x8 ldbf8(const void* p) {
  return *reinterpret_cast<const bf16x8*>(p);
}

static __device__ __forceinline__ void gload_lds16(const void* g, void* l) {
  __builtin_amdgcn_global_load_lds(
      (const __attribute__((address_space(1))) u32*)g,
      (__attribute__((address_space(3))) u32*)l, 16, 0, 0);
}

// ---------------------------------------------------------------- cvt f32->bf16 (fused x, W_qkv, W_o)
__global__ void cvt_all(const float* __restrict__ x, const float* __restrict__ wq,
                        const float* __restrict__ wo, u16* __restrict__ xb,
                        u16* __restrict__ wqb, u16* __restrict__ wob) {
  int i = blockIdx.x * 256 + threadIdx.x;  // grid 4096 -> 1,048,576 threads
  const float* s;
  u16* d;
  int j;
  if (i < 524288) {
    s = x; d = xb; j = i;
  } else if (i < 917504) {
    s = wq; d = wqb; j = i - 524288;
  } else {
    s = wo; d = wob; j = i - 917504;
  }
  const float4* p = reinterpret_cast<const float4*>(s) + (size_t)j * 2;
  float4 a = p[0], b = p[1];
  uint4 o;
  o.x = (u32)f2bf(a.x) | ((u32)f2bf(a.y) << 16);
  o.y = (u32)f2bf(a.z) | ((u32)f2bf(a.w) << 16);
  o.z = (u32)f2bf(b.x) | ((u32)f2bf(b.y) << 16);
  o.w = (u32)f2bf(b.z) | ((u32)f2bf(b.w) << 16);
  reinterpret_cast<uint4*>(d)[j] = o;
}

// ---------------------------------------------------------------- GEMM C = A*B^T + bias
// 128x128 tile, BK=64, 4 waves; 3 blocks/CU; XCD-chunked block remap.
template <bool BF16OUT>
__global__ __launch_bounds__(256, 3) void gemm_bt(const u16* __restrict__ A,
                                                  const u16* __restrict__ Bm,
                                                  const float* __restrict__ bias,
                                                  void* __restrict__ Cp,
                                                  int M, int N, int K) {
  __shared__ __align__(16) char As[128 * 64 * 2];
  __shared__ __align__(16) char Bs[128 * 64 * 2];
  const int tid = threadIdx.x;
  const int lane = tid & 63;
  const int wid = tid >> 6;
  const int fr = lane & 15, fg = lane >> 4;
  // XCD-aware bijective remap (nwg % 8 == 0 for both call sites)
  const int gx = gridDim.x, nwg = gx * gridDim.y;
  const int id = blockIdx.y * gx + blockIdx.x;
  const int nid = (id & 7) * (nwg >> 3) + (id >> 3);
  const int bm = nid / gx, bn = nid % gx;
  const int wm = (wid >> 1) * 64, wn = (wid & 1) * 64;

  f32x4 acc[4][4];
#pragma unroll
  for (int i = 0; i < 4; ++i)
#pragma unroll
    for (int j = 0; j < 4; ++j) acc[i][j] = (f32x4){0.f, 0.f, 0.f, 0.f};

  const int nk = K >> 6;
  for (int kt = 0; kt < nk; ++kt) {
#pragma unroll
    for (int it = 0; it < 4; ++it) {
      int q = it * 256 + tid;
      int row = q >> 3;
      int c = (q & 7) ^ (row & 7);  // pre-swizzled source chunk
      gload_lds16(A + (size_t)(bm * 128 + row) * K + kt * 64 + c * 8, As + q * 16);
      gload_lds16(Bm + (size_t)(bn * 128 + row) * K + kt * 64 + c * 8, Bs + q * 16);
    }
    __syncthreads();
#pragma unroll
    for (int mk = 0; mk < 2; ++mk) {
      bf16x8 af[4], bfr[4];
#pragma unroll
      for (int i = 0; i < 4; ++i) {
        int row = wm + i * 16 + fr;
        af[i] = ldbf8(As + ((row * 128 + mk * 64 + fg * 16) ^ ((row & 7) << 4)));
      }
#pragma unroll
      for (int j = 0; j < 4; ++j) {
        int row = wn + j * 16 + fr;
        bfr[j] = ldbf8(Bs + ((row * 128 + mk * 64 + fg * 16) ^ ((row & 7) << 4)));
      }
#pragma unroll
      for (int i = 0; i < 4; ++i)
#pragma unroll
        for (int j = 0; j < 4; ++j) acc[i][j] = MFMA16(af[i], bfr[j], acc[i][j]);
    }
    __syncthreads();
  }

#pragma unroll
  for (int j = 0; j < 4; ++j) {
    int col = bn * 128 + wn + j * 16 + fr;
    float bv = bias[col];
#pragma unroll
    for (int i = 0; i < 4; ++i) {
#pragma unroll
      for (int r = 0; r < 4; ++r) {
        int row = bm * 128 + wm + i * 16 + fg * 4 + r;
        float v = acc[i][j][r] + bv;
        if (BF16OUT)
          ((u16*)Cp)[(size_t)row * N + col] = f2bf(v);
        else
          ((float*)Cp)[(size_t)row * N + col] = v;
      }
    }
  }
}

// ---------------------------------------------------------------- GEMM 64x128 tile (fp32 out)
__global__ __launch_bounds__(256, 2) void gemm_bt64(const u16* __restrict__ A,
                                                    const u16* __restrict__ Bm,
                                                    const float* __restrict__ bias,
                                                    float* __restrict__ Cp,
                                                    int M, int N, int K) {
  __shared__ __align__(16) char As[64 * 64 * 2];
  __shared__ __align__(16) char Bs[128 * 64 * 2];
  const int tid = threadIdx.x;
  const int lane = tid & 63;
  const int wid = tid >> 6;
  const int fr = lane & 15, fg = lane >> 4;
  const int gx = gridDim.x, nwg = gx * gridDim.y;
  const int id = blockIdx.y * gx + blockIdx.x;
  const int nid = (id & 7) * (nwg >> 3) + (id >> 3);
  const int bm = nid / gx, bn = nid % gx;
  const int wm = (wid >> 1) * 32, wn = (wid & 1) * 64;

  f32x4 acc[2][4];
#pragma unroll
  for (int i = 0; i < 2; ++i)
#pragma unroll
    for (int j = 0; j < 4; ++j) acc[i][j] = (f32x4){0.f, 0.f, 0.f, 0.f};

  const int nk = K >> 6;
  for (int kt = 0; kt < nk; ++kt) {
#pragma unroll
    for (int it = 0; it < 2; ++it) {  // A: 512 chunks
      int q = it * 256 + tid;
      int row = q >> 3;
      int c = (q & 7) ^ (row & 7);
      gload_lds16(A + (size_t)(bm * 64 + row) * K + kt * 64 + c * 8, As + q * 16);
    }
#pragma unroll
    for (int it = 0; it < 4; ++it) {  // B: 1024 chunks
      int q = it * 256 + tid;
      int row = q >> 3;
      int c = (q & 7) ^ (row & 7);
      gload_lds16(Bm + (size_t)(bn * 128 + row) * K + kt * 64 + c * 8, Bs + q * 16);
    }
    __syncthreads();
#pragma unroll
    for (int mk = 0; mk < 2; ++mk) {
      bf16x8 af[2], bfr[4];
#pragma unroll
      for (int i = 0; i < 2; ++i) {
        int row = wm + i * 16 + fr;
        af[i] = ldbf8(As + ((row * 128 + mk * 64 + fg * 16) ^ ((row & 7) << 4)));
      }
#pragma unroll
      for (int j = 0; j < 4; ++j) {
        int row = wn + j * 16 + fr;
        bfr[j] = ldbf8(Bs + ((row * 128 + mk * 64 + fg * 16) ^ ((row & 7) << 4)));
      }
#pragma unroll
      for (int i = 0; i < 2; ++i)
#pragma unroll
        for (int j = 0; j < 4; ++j) acc[i][j] = MFMA16(af[i], bfr[j], acc[i][j]);
    }
    __syncthreads();
  }

#pragma unroll
  for (int j = 0; j < 4; ++j) {
    int col = bn * 128 + wn + j * 16 + fr;
    float bv = bias[col];
#pragma unroll
    for (int i = 0; i < 2; ++i) {
#pragma unroll
      for (int r = 0; r < 4; ++r) {
        int row = bm * 64 + wm + i * 16 + fg * 4 + r;
        Cp[(size_t)row * N + col] = acc[i][j][r] + bv;
      }
    }
  }
}

// ---------------------------------------------------------------- flash attention v15 (R21-verified best)
// 4 waves x 32 q-rows, 128-key dbuf tiles; K via global_load_lds direct
// (pre-swizzled source); V reg-staged with shuffle-free logical key order
// (phys 32m+16u+4g+e -> L 32m+8g+4u+e => lane-local PV A-frags); no-max exp2
// softmax; l via ones-MFMA; counted barrier vmcnt(4)+lgkmcnt(0); setprio.
__global__ __launch_bounds__(256, 2) void attn_fwd(const u16* __restrict__ qkv,
                                                   u16* __restrict__ aout) {
  const int id = blockIdx.y * gridDim.x + blockIdx.x;  // 0..511
  const int xcd = id & 7, slot = id >> 3;
  const int bh = xcd * 4 + (slot >> 4);
  const int qt = slot & 15;
  const int b = bh >> 4, h = bh & 15;
  const int tid = threadIdx.x, lane = tid & 63, wid = tid >> 6;
  const int fr = lane & 15, fg = (lane >> 4) & 3;

  __shared__ __align__(16) char Ks[2][2][64 * 128];   // [buf][sub] swizzled [key][d]
  __shared__ __align__(16) char VTs[2][2][64 * 128];  // [buf][sub] swizzled [d][lkey]

  const int q0 = qt * 128 + wid * 32;  // 32 q-rows per wave
  const size_t bS = (size_t)b * 2048;
  const u16* kbase = qkv + bS * 3072 + h * 192 + 64;
  const u16* vbase = qkv + bS * 3072 + h * 192 + 128;

  // V staging geometry (loop-invariant)
  const int vs2 = (tid >> 3) * 2;
  const int vdc = (tid & 7) * 8;
  const int vl0 = 32 * (vs2 >> 5) + 8 * ((vs2 >> 2) & 3) + 4 * ((vs2 >> 4) & 1) +
                  (vs2 & 3);  // shuffle-free logical slot (even)
  int wof[8];
#pragma unroll
  for (int j = 0; j < 8; ++j) {
    int d = vdc + j;
    wof[j] = ((d * 128 + vl0 * 2) ^ ((((d & 7) ^ ((d >> 3) & 7))) << 4));
    asm volatile("" : "+v"(wof[j]));
  }
  int kro[2];
#pragma unroll
  for (int mk = 0; mk < 2; ++mk) {
    kro[mk] = ((fr * 128 + mk * 64 + fg * 16) ^ ((fr & 7) << 4));
    asm volatile("" : "+v"(kro[mk]));
  }
  int vadr[4][2];
#pragma unroll
  for (int tp = 0; tp < 4; ++tp)
#pragma unroll
    for (int mk = 0; mk < 2; ++mk) {
      int d = tp * 16 + fr;
      int swz = (((d & 7) ^ ((d >> 3) & 7)) << 4);
      vadr[tp][mk] = ((d * 128 + mk * 64 + fg * 16) ^ swz);
      asm volatile("" : "+v"(vadr[tp][mk]));
    }

  bf16x8 qf[2][2];
#pragma unroll
  for (int qs = 0; qs < 2; ++qs)
#pragma unroll
    for (int mk = 0; mk < 2; ++mk) {
      bf16x8 v =
          ldbf8(qkv + (bS + q0 + qs * 16 + fr) * 3072 + h * 192 + mk * 32 + fg * 8);
#pragma unroll
      for (int e = 0; e < 8; ++e) v[e] = (__bf16)((float)v[e] * 0.1803368801f);
      qf[qs][mk] = v;
    }

  const u32 one2 = 0x3F803F80u;
  const u32x4 onev = {one2, one2, one2, one2};
  const bf16x8 onesf = __builtin_bit_cast(bf16x8, onev);
  float zs = 0.f;
  asm volatile("" : "+v"(zs));
  const f32x4 zacc = {zs, zs, zs, zs};

  f32x4 oacc0[4], oacc1[4];
#pragma unroll
  for (int t = 0; t < 4; ++t) {
    oacc0[t] = (f32x4){0.f, 0.f, 0.f, 0.f};
    oacc1[t] = (f32x4){0.f, 0.f, 0.f, 0.f};
  }
  f32x4 lacc0 = (f32x4){0.f, 0.f, 0.f, 0.f};
  f32x4 lacc1 = (f32x4){0.f, 0.f, 0.f, 0.f};

// K tile (128 keys) -> Ks[BUF] via 4 gload_lds/thread (pre-swizzled source)
#define KISSUE(S0, BUF)                                                        \
  _Pragma("unroll") for (int it = 0; it < 2; ++it) {                           \
    int q = it * 256 + tid;                                                    \
    int row = q >> 3;                                                          \
    int c = (q & 7) ^ (row & 7);                                               \
    gload_lds16(kbase + (size_t)((S0) + row) * 3072 + c * 8,                   \
                Ks[BUF][0] + q * 16);                                          \
    gload_lds16(kbase + (size_t)((S0) + 64 + row) * 3072 + c * 8,              \
                Ks[BUF][1] + q * 16);                                          \
  }

#define LOADV(S0, V0, V1, V2, V3)                                                  \
  V0 = *reinterpret_cast<const uint4*>(vbase + (size_t)((S0) + vs2) * 3072 + vdc); \
  V1 = *reinterpret_cast<const uint4*>(vbase + (size_t)((S0) + vs2 + 1) * 3072 + vdc); \
  V2 = *reinterpret_cast<const uint4*>(vbase + (size_t)((S0) + 64 + vs2) * 3072 + vdc); \
  V3 = *reinterpret_cast<const uint4*>(vbase + (size_t)((S0) + 64 + vs2 + 1) * 3072 + vdc);

#define STAGEV1(VTP, V0, V1)                           \
  {                                                    \
    const u16* e0 = reinterpret_cast<const u16*>(&V0); \
    const u16* e1 = reinterpret_cast<const u16*>(&V1); \
    _Pragma("unroll") for (int j = 0; j < 8; ++j) {    \
      u32 w = (u32)e0[j] | ((u32)e1[j] << 16);         \
      *reinterpret_cast<u32*>((VTP) + wof[j]) = w;     \
    }                                                  \
  }

#define STAGEV(BUF, V0, V1, V2, V3)   \
  {                                   \
    STAGEV1(VTs[BUF][0], V0, V1);     \
    STAGEV1(VTs[BUF][1], V2, V3);     \
  }

// counted barrier: K(t+1) gloads (4, older) drained; V(t+2) loads (4) fly on
#define BARC()                                                   \
  {                                                              \
    __builtin_amdgcn_sched_barrier(0);                           \
    asm volatile("s_waitcnt vmcnt(4) lgkmcnt(0)" ::: "memory");  \
    __builtin_amdgcn_s_barrier();                                \
    __builtin_amdgcn_sched_barrier(0);                           \
  }

#define COMPUTE1(KSP, VTP)                                                     \
  {                                                                            \
    f32x4 sc0[4], sc1[4];                                                      \
    __builtin_amdgcn_s_setprio(1);                                             \
    _Pragma("unroll") for (int t = 0; t < 4; ++t) {                            \
      bf16x8 kf0 = ldbf8((KSP) + kro[0] + t * 2048);                           \
      bf16x8 kf1 = ldbf8((KSP) + kro[1] + t * 2048);                           \
      sc0[t] = MFMA16(kf0, qf[0][0], zacc);                                    \
      sc0[t] = MFMA16(kf1, qf[0][1], sc0[t]);                                  \
      sc1[t] = MFMA16(kf0, qf[1][0], zacc);                                    \
      sc1[t] = MFMA16(kf1, qf[1][1], sc1[t]);                                  \
    }                                                                          \
    __builtin_amdgcn_s_setprio(0);                                             \
    u32 Wp0[2][4], Wp1[2][4];                                                  \
    _Pragma("unroll") for (int t = 0; t < 4; ++t) {                            \
      Wp0[0][t] = pack2(__builtin_amdgcn_exp2f(sc0[t][0]),                     \
                        __builtin_amdgcn_exp2f(sc0[t][1]));                    \
      Wp0[1][t] = pack2(__builtin_amdgcn_exp2f(sc0[t][2]),                     \
                        __builtin_amdgcn_exp2f(sc0[t][3]));                    \
      Wp1[0][t] = pack2(__builtin_amdgcn_exp2f(sc1[t][0]),                     \
                        __builtin_amdgcn_exp2f(sc1[t][1]));                    \
      Wp1[1][t] = pack2(__builtin_amdgcn_exp2f(sc1[t][2]),                     \
                        __builtin_amdgcn_exp2f(sc1[t][3]));                    \
    }                                                                          \
    _Pragma("unroll") for (int mk = 0; mk < 2; ++mk) {                         \
      u32x4 pk0, pk1;                                                          \
      pk0.x = Wp0[0][2 * mk];                                                  \
      pk0.y = Wp0[1][2 * mk];                                                  \
      pk0.z = Wp0[0][2 * mk + 1];                                              \
      pk0.w = Wp0[1][2 * mk + 1];                                              \
      pk1.x = Wp1[0][2 * mk];                                                  \
      pk1.y = Wp1[1][2 * mk];                                                  \
      pk1.z = Wp1[0][2 * mk + 1];                                              \
      pk1.w = Wp1[1][2 * mk + 1];                                              \
      bf16x8 pa0 = __builtin_bit_cast(bf16x8, pk0);                            \
      bf16x8 pa1 = __builtin_bit_cast(bf16x8, pk1);                            \
      __builtin_amdgcn_s_setprio(1);                                           \
      lacc0 = MFMA16(pa0, onesf, lacc0);                                       \
      lacc1 = MFMA16(pa1, onesf, lacc1);                                       \
      _Pragma("unroll") for (int tp = 0; tp < 4; ++tp) {                       \
        bf16x8 vf = ldbf8((VTP) + vadr[tp][mk]);                               \
        oacc0[tp] = MFMA16(pa0, vf, oacc0[tp]);                                \
        oacc1[tp] = MFMA16(pa1, vf, oacc1[tp]);                                \
      }                                                                        \
      __builtin_amdgcn_s_setprio(0);                                           \
    }                                                                          \
  }

#define COMPUTE(BUF)                   \
  {                                    \
    COMPUTE1(Ks[BUF][0], VTs[BUF][0]); \
    COMPUTE1(Ks[BUF][1], VTs[BUF][1]); \
  }

  uint4 va0, va1, va2, va3;
  uint4 vb0, vb1, vb2, vb3;
  // prologue: K(0)->Ks[0] (gload); V(0)->va->VTs[0]; V(1)->vb; barrier.
  KISSUE(0, 0);
  __builtin_amdgcn_sched_barrier(0);
  LOADV(0, va0, va1, va2, va3);
  STAGEV(0, va0, va1, va2, va3);
  LOADV(128, vb0, vb1, vb2, vb3);
  BARC();
  for (int kv = 0; kv < 16; kv += 2) {
    // phase A (tile kv, buf0): K(kv+1)->Ks[1]; V(kv+2)->va; V(kv+1)->VTs[1]
    {
      int sk = (kv + 1 < 16) ? (kv + 1) * 128 : 0;  // tail: harmless write
      KISSUE(sk, 1);
    }
    __builtin_amdgcn_sched_barrier(0);
    {
      int sv = (kv + 2 < 16) ? (kv + 2) * 128 : 0;  // tail: harmless load
      LOADV(sv, va0, va1, va2, va3);
    }
    STAGEV(1, vb0, vb1, vb2, vb3);
    COMPUTE(0);
    BARC();
    // phase B (tile kv+1, buf1): K(kv+2)->Ks[0]; V(kv+3)->vb; V(kv+2)->VTs[0]
    {
      int sk = (kv + 2 < 16) ? (kv + 2) * 128 : 0;
      KISSUE(sk, 0);
    }
    __builtin_amdgcn_sched_barrier(0);
    {
      int sv = (kv + 3 < 16) ? (kv + 3) * 128 : 128;
      LOADV(sv, vb0, vb1, vb2, vb3);
    }
    STAGEV(0, va0, va1, va2, va3);
    COMPUTE(1);
    BARC();
  }
#undef KISSUE
#undef LOADV
#undef STAGEV1
#undef STAGEV
#undef BARC
#undef COMPUTE1
#undef COMPUTE

  {
    float invb0[4], invb1[4];
#pragma unroll
    for (int r = 0; r < 4; ++r) {
      invb0[r] = 1.f / lacc0[r];
      invb1[r] = 1.f / lacc1[r];
    }
#pragma unroll
    for (int tp = 0; tp < 4; ++tp) {
#pragma unroll
      for (int r = 0; r < 4; ++r) {
        int row0 = q0 + fg * 4 + r;
        aout[(bS + row0) * 1024 + h * 64 + tp * 16 + fr] =
            f2bf(oacc0[tp][r] * invb0[r]);
        int row1 = q0 + 16 + fg * 4 + r;
        aout[(bS + row1) * 1024 + h * 64 + tp * 16 + fr] =
            f2bf(oacc1[tp][r] * invb1[r]);
      }
    }
  }
}

// ---------------------------------------------------------------- launch
extern "C" void kernel_launch(void* const* d_in, const int* in_sizes, int n_in,
                              void* d_out, int out_size, void* d_ws, size_t ws_size,
                              hipStream_t stream) {
  const float* x = (const float*)d_in[0];
  const float* Wqkv = (const float*)d_in[1];
  const float* bqkv = (const float*)d_in[2];
  const float* Wo = (const float*)d_in[3];
  const float* bo = (const float*)d_in[4];
  float* out = (float*)d_out;
  char* ws = (char*)d_ws;

  u16* xb = (u16*)(ws);                       //  8,388,608  x bf16 [4096,1024]
  u16* wqb = (u16*)(ws + 8388608);            //  6,291,456  W_qkv bf16 [3072,1024]
  u16* wob = (u16*)(ws + 14680064);           //  2,097,152  W_o bf16 [1024,1024]
  u16* qkvb = (u16*)(ws + 16777216);          // 25,165,824  qkv bf16 [4096,3072]
  u16* attb = (u16*)(ws + 41943040);          //  8,388,608  attn out bf16 [4096,1024]

  cvt_all<<<4096, 256, 0, stream>>>(x, Wqkv, Wo, xb, wqb, wob);

  gemm_bt<true><<<dim3(24, 32), 256, 0, stream>>>(xb, wqb, bqkv, qkvb, 4096, 3072, 1024);
  attn_fwd<<<dim3(16, 32), 256, 0, stream>>>(qkvb, attb);
  gemm_bt64<<<dim3(8, 64), 256, 0, stream>>>(attb, wob, bo, out, 4096, 1024, 1024);
}